// Round 2
// baseline (1420.253 us; speedup 1.0000x reference)
//
#include <hip/hip_runtime.h>
#include <hip/hip_bf16.h>

#define NN 2048
#define NE 65536
#define NG 32
#define CIN 128
#define CED 32
#define CLAT 64
#define CFA 16
#define CNB 5
#define NL 5

__device__ __forceinline__ float silu_f(float v) { return v / (1.0f + __expf(-v)); }

// ---------------- init s: s = ((x@W_atom+b_atom+tnode) @ W_at + b_at) + z@W_lat+b_lat ----------
__global__ void k_init_s(const float* __restrict__ x, const float* __restrict__ t,
                         const float* __restrict__ z, const int* __restrict__ batch,
                         const float* __restrict__ Wt_a, const float* __restrict__ bt_a,
                         const float* __restrict__ W_atom, const float* __restrict__ b_atom,
                         const float* __restrict__ W_lat, const float* __restrict__ b_lat,
                         const float* __restrict__ W_at, const float* __restrict__ b_at,
                         float* __restrict__ s)
{
    int n = blockIdx.x, c = threadIdx.x;
    __shared__ float tmp[CIN];
    float tg = t[batch[n]];
    float acc = b_atom[c] + tg * Wt_a[c] + bt_a[c];
#pragma unroll
    for (int k = 0; k < CFA; k++) acc += x[n * CFA + k] * W_atom[k * CIN + c];
    tmp[c] = acc;
    __syncthreads();
    float acc2 = b_at[c] + b_lat[c];
    for (int d4 = 0; d4 < CIN / 4; d4++) {
        float4 f = *(const float4*)&tmp[4 * d4];
        acc2 += f.x * W_at[(4 * d4 + 0) * CIN + c] + f.y * W_at[(4 * d4 + 1) * CIN + c]
              + f.z * W_at[(4 * d4 + 2) * CIN + c] + f.w * W_at[(4 * d4 + 3) * CIN + c];
    }
    for (int k = 0; k < CLAT; k++) acc2 += z[n * CLAT + k] * W_lat[k * CIN + c];
    s[n * CIN + c] = acc2;
}

// ---------------- init e + dense-map scatter (last edge id wins via atomicMax) -----------------
__global__ void k_init_e(const float* __restrict__ ea, const float* __restrict__ t,
                         const int* __restrict__ beg, const int* __restrict__ jj, const int* __restrict__ ii,
                         const float* __restrict__ Wt_b, const float* __restrict__ bt_b,
                         const float* __restrict__ W_bond, const float* __restrict__ b_bond,
                         const float* __restrict__ W_bt, const float* __restrict__ b_bt,
                         float* __restrict__ e, int* __restrict__ map)
{
    int le = threadIdx.x >> 5, c = threadIdx.x & 31;
    int k = blockIdx.x * 8 + le;
    __shared__ float tmp[8][CED];
    float tg = t[beg[k]];
    float acc = b_bond[c] + tg * Wt_b[c] + bt_b[c];
#pragma unroll
    for (int b = 0; b < CNB; b++) acc += ea[k * CNB + b] * W_bond[b * CED + c];
    tmp[le][c] = acc;
    __syncthreads();
    float acc2 = b_bt[c];
#pragma unroll
    for (int d = 0; d < CED; d++) acc2 += tmp[le][d] * W_bt[d * CED + c];
    e[k * CED + c] = acc2;
    if (c == 0) atomicMax(&map[jj[k] * NN + ii[k]], k);
}

// ---------------- msg GEMM + fused segment_sum: agg[i[k]] += silu(cat(s[i],s[j],e) @ Wmsg + b) --
__global__ void k_msg(const float* __restrict__ s, const float* __restrict__ e,
                      const int* __restrict__ ii, const int* __restrict__ jj,
                      const float* __restrict__ Wmsg, const float* __restrict__ bmsg,
                      float* __restrict__ agg)
{
    const int TE = 16, K = 2 * CIN + CED; // 288
    int tid = threadIdx.x;
    int e0 = blockIdx.x * TE;
    __shared__ float feat[TE][K];
    __shared__ int si[TE];
    if (tid < TE) si[tid] = ii[e0 + tid];
    for (int idx = tid; idx < TE * K; idx += 128) {
        int le = idx / K, d = idx - le * K;
        int k = e0 + le;
        float v;
        if (d < CIN) v = s[ii[k] * CIN + d];
        else if (d < 2 * CIN) v = s[jj[k] * CIN + (d - CIN)];
        else v = e[k * CED + (d - 2 * CIN)];
        feat[le][d] = v;
    }
    __syncthreads();
    int c = tid;
    float acc[TE];
#pragma unroll
    for (int t2 = 0; t2 < TE; t2++) acc[t2] = 0.f;
    for (int d4 = 0; d4 < K / 4; d4++) {
        float w0 = Wmsg[(4 * d4 + 0) * CIN + c];
        float w1 = Wmsg[(4 * d4 + 1) * CIN + c];
        float w2 = Wmsg[(4 * d4 + 2) * CIN + c];
        float w3 = Wmsg[(4 * d4 + 3) * CIN + c];
#pragma unroll
        for (int t2 = 0; t2 < TE; t2++) {
            float4 f = *(const float4*)&feat[t2][4 * d4];
            acc[t2] += f.x * w0 + f.y * w1 + f.z * w2 + f.w * w3;
        }
    }
    float bb = bmsg[c];
#pragma unroll
    for (int t2 = 0; t2 < TE; t2++) {
        float v = silu_f(acc[t2] + bb);
        atomicAdd(&agg[si[t2] * CIN + c], v);
    }
}

// ---------------- node update: s = s + silu(cat(s, agg) @ Wnode + bnode) -----------------------
__global__ void k_node(float* __restrict__ s, const float* __restrict__ agg,
                       const float* __restrict__ Wnode, const float* __restrict__ bnode)
{
    int n = blockIdx.x, c = threadIdx.x;
    __shared__ float feat[2 * CIN];
    float sold = s[n * CIN + c];
    feat[c] = sold;
    feat[CIN + c] = agg[n * CIN + c];
    __syncthreads();
    float acc = bnode[c];
    for (int d4 = 0; d4 < (2 * CIN) / 4; d4++) {
        float4 f = *(const float4*)&feat[4 * d4];
        acc += f.x * Wnode[(4 * d4 + 0) * CIN + c] + f.y * Wnode[(4 * d4 + 1) * CIN + c]
             + f.z * Wnode[(4 * d4 + 2) * CIN + c] + f.w * Wnode[(4 * d4 + 3) * CIN + c];
    }
    s[n * CIN + c] = sold + silu_f(acc);
}

// ---------------- edge update: e = e + silu(cat(s[i], s[j], e) @ Wedge + bedge) ----------------
__global__ void k_edge(const float* __restrict__ s, float* __restrict__ e,
                       const int* __restrict__ ii, const int* __restrict__ jj,
                       const float* __restrict__ Wedge, const float* __restrict__ bedge)
{
    const int TE = 16, K = 288, KP = 292;
    int tid = threadIdx.x;
    int e0 = blockIdx.x * TE;
    __shared__ float feat[TE][KP];
    for (int idx = tid; idx < TE * K; idx += 128) {
        int le = idx / K, d = idx - le * K;
        int k = e0 + le;
        float v;
        if (d < CIN) v = s[ii[k] * CIN + d];
        else if (d < 2 * CIN) v = s[jj[k] * CIN + (d - CIN)];
        else v = e[k * CED + (d - 2 * CIN)];
        feat[le][d] = v;
    }
    __syncthreads();
    int c = tid & 31, g = tid >> 5;
    float acc[4] = {0.f, 0.f, 0.f, 0.f};
    for (int d4 = 0; d4 < K / 4; d4++) {
        float w0 = Wedge[(4 * d4 + 0) * CED + c];
        float w1 = Wedge[(4 * d4 + 1) * CED + c];
        float w2 = Wedge[(4 * d4 + 2) * CED + c];
        float w3 = Wedge[(4 * d4 + 3) * CED + c];
#pragma unroll
        for (int t2 = 0; t2 < 4; t2++) {
            float4 f = *(const float4*)&feat[g * 4 + t2][4 * d4];
            acc[t2] += f.x * w0 + f.y * w1 + f.z * w2 + f.w * w3;
        }
    }
    float bb = bedge[c];
#pragma unroll
    for (int t2 = 0; t2 < 4; t2++) {
        int k = e0 + g * 4 + t2;
        e[k * CED + c] += silu_f(acc[t2] + bb);
    }
}

// ---------------- post node: s2 = silu(s@Wsh+bsh); al = s2@Wal+bal -> latent/atoms outputs -----
__global__ void k_post_node(const float* __restrict__ s,
                            const float* __restrict__ Wsh, const float* __restrict__ bsh,
                            const float* __restrict__ Wal, const float* __restrict__ bal,
                            float* __restrict__ s2, float* __restrict__ out)
{
    int n = blockIdx.x, c = threadIdx.x;
    __shared__ float sh[CIN];
    __shared__ float s2sh[CIN];
    sh[c] = s[n * CIN + c];
    __syncthreads();
    float acc = bsh[c];
    for (int d4 = 0; d4 < CIN / 4; d4++) {
        float4 f = *(const float4*)&sh[4 * d4];
        acc += f.x * Wsh[(4 * d4 + 0) * CIN + c] + f.y * Wsh[(4 * d4 + 1) * CIN + c]
             + f.z * Wsh[(4 * d4 + 2) * CIN + c] + f.w * Wsh[(4 * d4 + 3) * CIN + c];
    }
    float v = silu_f(acc);
    s2[n * CIN + c] = v;
    s2sh[c] = v;
    __syncthreads();
    if (c < CFA + CLAT) {
        float acc2 = bal[c];
        const int AO = CFA + CLAT; // 80
        for (int d4 = 0; d4 < CIN / 4; d4++) {
            float4 f = *(const float4*)&s2sh[4 * d4];
            acc2 += f.x * Wal[(4 * d4 + 0) * AO + c] + f.y * Wal[(4 * d4 + 1) * AO + c]
                  + f.z * Wal[(4 * d4 + 2) * AO + c] + f.w * Wal[(4 * d4 + 3) * AO + c];
        }
        if (c < CFA) out[NN * CLAT + n * CFA + c] = acc2;      // atoms_pred
        else         out[n * CLAT + (c - CFA)] = acc2;         // latent_pred
    }
}

// ---------------- post edge: e_sym gather/symmetrize, f = silu(s2[i]+s2[j]+e_sym@Wbm+bbm), bonds
__global__ void k_post_edge(const float* __restrict__ s2, const float* __restrict__ e,
                            const int* __restrict__ ii, const int* __restrict__ jj, const int* __restrict__ map,
                            const float* __restrict__ Wbm, const float* __restrict__ bbm,
                            const float* __restrict__ Wbl, const float* __restrict__ bbl,
                            float* __restrict__ out)
{
    const int TE = 4;
    int tid = threadIdx.x;
    int e0 = blockIdx.x * TE;
    __shared__ float esym[TE][CED];
    __shared__ float fsh[TE][CIN];
    for (int idx = tid; idx < TE * CED; idx += 128) {
        int le = idx >> 5, d = idx & 31;
        int k = e0 + le;
        int jf = jj[k], ifw = ii[k];
        int kf = map[jf * NN + ifw];
        int kb = map[ifw * NN + jf];
        if (kf < 0) kf = k; // safety; map[j,i] always set by edge k itself
        float v = e[kf * CED + d];
        if (kb >= 0) v += e[kb * CED + d];
        esym[le][d] = 0.5f * v;
    }
    __syncthreads();
    int c = tid;
#pragma unroll
    for (int le = 0; le < TE; le++) {
        int k = e0 + le;
        float acc = bbm[c] + s2[ii[k] * CIN + c] + s2[jj[k] * CIN + c];
        for (int d4 = 0; d4 < CED / 4; d4++) {
            float4 f = *(const float4*)&esym[le][4 * d4];
            acc += f.x * Wbm[(4 * d4 + 0) * CIN + c] + f.y * Wbm[(4 * d4 + 1) * CIN + c]
                 + f.z * Wbm[(4 * d4 + 2) * CIN + c] + f.w * Wbm[(4 * d4 + 3) * CIN + c];
        }
        fsh[le][c] = silu_f(acc);
    }
    __syncthreads();
    if (tid < TE * CNB) {
        int le = tid / CNB, b = tid - le * CNB;
        float acc = bbl[b];
        for (int d = 0; d < CIN; d++) acc += fsh[le][d] * Wbl[d * CNB + b];
        out[NN * CLAT + NN * CFA + (e0 + le) * CNB + b] = acc;
    }
}

extern "C" void kernel_launch(void* const* d_in, const int* in_sizes, int n_in,
                              void* d_out, int out_size, void* d_ws, size_t ws_size,
                              hipStream_t stream) {
    const float* x      = (const float*)d_in[0];
    const float* t      = (const float*)d_in[1];
    const float* z      = (const float*)d_in[2];
    const int*   eidx   = (const int*)d_in[3];
    const int*   jj     = eidx;        // edge_index[0] = j (source)
    const int*   ii     = eidx + NE;   // edge_index[1] = i (target)
    const float* ea     = (const float*)d_in[4];
    const int*   batch  = (const int*)d_in[5];
    const int*   beg    = (const int*)d_in[6];
    const float* Wt_a   = (const float*)d_in[7];
    const float* bt_a   = (const float*)d_in[8];
    const float* Wt_b   = (const float*)d_in[9];
    const float* bt_b   = (const float*)d_in[10];
    const float* W_atom = (const float*)d_in[11];
    const float* b_atom = (const float*)d_in[12];
    const float* W_bond = (const float*)d_in[13];
    const float* b_bond = (const float*)d_in[14];
    const float* W_lat  = (const float*)d_in[15];
    const float* b_lat  = (const float*)d_in[16];
    const float* W_at   = (const float*)d_in[17];
    const float* b_at   = (const float*)d_in[18];
    const float* W_bt   = (const float*)d_in[19];
    const float* b_bt   = (const float*)d_in[20];
    const float* Wmsg   = (const float*)d_in[21];
    const float* bmsg   = (const float*)d_in[22];
    const float* Wnode  = (const float*)d_in[23];
    const float* bnode  = (const float*)d_in[24];
    const float* Wedge  = (const float*)d_in[25];
    const float* bedge  = (const float*)d_in[26];
    const float* Wsh    = (const float*)d_in[27];
    const float* bsh    = (const float*)d_in[28];
    const float* Wbm    = (const float*)d_in[29];
    const float* bbm    = (const float*)d_in[30];
    const float* Wbl    = (const float*)d_in[31];
    const float* bbl    = (const float*)d_in[32];
    const float* Wal    = (const float*)d_in[33];
    const float* bal    = (const float*)d_in[34];

    float* s   = (float*)d_ws;                 // N*128 f32
    float* e   = s + (size_t)NN * CIN;         // E*32 f32
    float* agg = e + (size_t)NE * CED;         // N*128 f32
    float* s2  = agg + (size_t)NN * CIN;       // N*128 f32
    int*   map = (int*)(s2 + (size_t)NN * CIN);// N*N i32
    float* out = (float*)d_out;

    hipMemsetAsync(map, 0xFF, (size_t)NN * NN * sizeof(int), stream); // -1
    k_init_s<<<NN, CIN, 0, stream>>>(x, t, z, batch, Wt_a, bt_a, W_atom, b_atom,
                                     W_lat, b_lat, W_at, b_at, s);
    k_init_e<<<NE / 8, 256, 0, stream>>>(ea, t, beg, jj, ii, Wt_b, bt_b, W_bond, b_bond,
                                         W_bt, b_bt, e, map);
    for (int l = 0; l < NL; l++) {
        hipMemsetAsync(agg, 0, (size_t)NN * CIN * sizeof(float), stream);
        k_msg<<<NE / 16, 128, 0, stream>>>(s, e, ii, jj,
                                           Wmsg + (size_t)l * 288 * CIN, bmsg + l * CIN, agg);
        k_node<<<NN, CIN, 0, stream>>>(s, agg, Wnode + (size_t)l * 256 * CIN, bnode + l * CIN);
        k_edge<<<NE / 16, 128, 0, stream>>>(s, e, ii, jj,
                                            Wedge + (size_t)l * 288 * CED, bedge + l * CED);
    }
    k_post_node<<<NN, CIN, 0, stream>>>(s, Wsh, bsh, Wal, bal, s2, out);
    k_post_edge<<<NE / 4, 128, 0, stream>>>(s2, e, ii, jj, map, Wbm, bbm, Wbl, bbl, out);
}

// Round 3
// 628.973 us; speedup vs baseline: 2.2581x; 2.2581x over previous
//
#include <hip/hip_runtime.h>
#include <hip/hip_bf16.h>

#define NN 2048
#define NE 65536
#define NG 32
#define CIN 128
#define CED 32
#define CLAT 64
#define CFA 16
#define CNB 5
#define NL 5

typedef __attribute__((ext_vector_type(8))) short bf16x8;
typedef __attribute__((ext_vector_type(4))) float f32x4;

__device__ __forceinline__ float silu_f(float v) { return v / (1.0f + __expf(-v)); }
__device__ __forceinline__ short f2bs(float v) {
    __hip_bfloat16 h = __float2bfloat16(v);
    return *reinterpret_cast<short*>(&h);
}

// ---------------- pack Wmsg/Wedge into MFMA B-fragment order: [l][kt][nt][lane][8] -------------
__global__ void k_pack_w(const float* __restrict__ Wmsg, const float* __restrict__ Wedge,
                         short* __restrict__ Wpm, short* __restrict__ Wpe)
{
    int idx = blockIdx.x * 256 + threadIdx.x;
    if (idx < NL * 9 * 8 * 64 * 8) { // 184320
        int j = idx & 7; int t = idx >> 3;
        int lane = t & 63; t >>= 6;
        int nt = t & 7; t >>= 3;
        int kt = t % 9; int l = t / 9;
        int k = kt * 32 + (lane >> 4) * 8 + j;
        int n = nt * 16 + (lane & 15);
        Wpm[idx] = f2bs(Wmsg[((size_t)l * 288 + k) * CIN + n]);
    }
    if (idx < NL * 9 * 2 * 64 * 8) { // 46080
        int j = idx & 7; int t = idx >> 3;
        int lane = t & 63; t >>= 6;
        int nt = t & 1; t >>= 1;
        int kt = t % 9; int l = t / 9;
        int k = kt * 32 + (lane >> 4) * 8 + j;
        int n = nt * 16 + (lane & 15);
        Wpe[idx] = f2bs(Wedge[((size_t)l * 288 + k) * CED + n]);
    }
}

// ---------------- init s (+ bf16 shadow) -------------------------------------------------------
__global__ void k_init_s(const float* __restrict__ x, const float* __restrict__ t,
                         const float* __restrict__ z, const int* __restrict__ batch,
                         const float* __restrict__ Wt_a, const float* __restrict__ bt_a,
                         const float* __restrict__ W_atom, const float* __restrict__ b_atom,
                         const float* __restrict__ W_lat, const float* __restrict__ b_lat,
                         const float* __restrict__ W_at, const float* __restrict__ b_at,
                         float* __restrict__ s, short* __restrict__ s_bf)
{
    int n = blockIdx.x, c = threadIdx.x;
    __shared__ float tmp[CIN];
    float tg = t[batch[n]];
    float acc = b_atom[c] + tg * Wt_a[c] + bt_a[c];
#pragma unroll
    for (int k = 0; k < CFA; k++) acc += x[n * CFA + k] * W_atom[k * CIN + c];
    tmp[c] = acc;
    __syncthreads();
    float acc2 = b_at[c] + b_lat[c];
    for (int d4 = 0; d4 < CIN / 4; d4++) {
        float4 f = *(const float4*)&tmp[4 * d4];
        acc2 += f.x * W_at[(4 * d4 + 0) * CIN + c] + f.y * W_at[(4 * d4 + 1) * CIN + c]
              + f.z * W_at[(4 * d4 + 2) * CIN + c] + f.w * W_at[(4 * d4 + 3) * CIN + c];
    }
    for (int k = 0; k < CLAT; k++) acc2 += z[n * CLAT + k] * W_lat[k * CIN + c];
    s[n * CIN + c] = acc2;
    s_bf[n * CIN + c] = f2bs(acc2);
}

// ---------------- init e (+ bf16 shadow) + dense map scatter -----------------------------------
__global__ void k_init_e(const float* __restrict__ ea, const float* __restrict__ t,
                         const int* __restrict__ beg, const int* __restrict__ jj, const int* __restrict__ ii,
                         const float* __restrict__ Wt_b, const float* __restrict__ bt_b,
                         const float* __restrict__ W_bond, const float* __restrict__ b_bond,
                         const float* __restrict__ W_bt, const float* __restrict__ b_bt,
                         float* __restrict__ e, short* __restrict__ e_bf, int* __restrict__ map)
{
    int le = threadIdx.x >> 5, c = threadIdx.x & 31;
    int k = blockIdx.x * 8 + le;
    __shared__ float tmp[8][CED];
    float tg = t[beg[k]];
    float acc = b_bond[c] + tg * Wt_b[c] + bt_b[c];
#pragma unroll
    for (int b = 0; b < CNB; b++) acc += ea[k * CNB + b] * W_bond[b * CED + c];
    tmp[le][c] = acc;
    __syncthreads();
    float acc2 = b_bt[c];
#pragma unroll
    for (int d = 0; d < CED; d++) acc2 += tmp[le][d] * W_bt[d * CED + c];
    e[k * CED + c] = acc2;
    e_bf[k * CED + c] = f2bs(acc2);
    if (c == 0) atomicMax(&map[jj[k] * NN + ii[k]], k);
}

// ---------------- msg GEMM (MFMA) + fused segment_sum ------------------------------------------
// 64 edges/block, 256 thr (4 waves), wave = 16 edges x 128 ch, K=288 in 9 steps of 32.
__global__ __launch_bounds__(256) void k_msg_mfma(
    const short* __restrict__ s_bf, const short* __restrict__ e_bf,
    const int* __restrict__ ii, const int* __restrict__ jj,
    const short* __restrict__ Wp, const float* __restrict__ bmsg,
    float* __restrict__ agg)
{
    __shared__ short feat[64 * 296]; // rows padded to 296 bf16 (592B, 16B aligned)
    __shared__ int sii[64], sjj[64];
    int tid = threadIdx.x;
    int e0 = blockIdx.x * 64;
    if (tid < 64) sii[tid] = ii[e0 + tid];
    else if (tid < 128) sjj[tid - 64] = jj[e0 + tid - 64];
    __syncthreads();
    // gather cat(s[i], s[j], e) as bf16, 16B chunks: 36 per edge (16 + 16 + 4)
    for (int idx = tid; idx < 64 * 36; idx += 256) {
        int kl = idx / 36, c = idx - kl * 36;
        uint4 v;
        if (c < 16)      v = ((const uint4*)s_bf)[(size_t)sii[kl] * 16 + c];
        else if (c < 32) v = ((const uint4*)s_bf)[(size_t)sjj[kl] * 16 + (c - 16)];
        else             v = ((const uint4*)e_bf)[(size_t)(e0 + kl) * 4 + (c - 32)];
        ((uint4*)feat)[kl * 37 + c] = v;
    }
    __syncthreads();
    int lane = tid & 63, w = tid >> 6;
    int quad = lane >> 4, n16 = lane & 15;
    f32x4 acc[8];
#pragma unroll
    for (int t2 = 0; t2 < 8; t2++) acc[t2] = (f32x4){0.f, 0.f, 0.f, 0.f};
    const short* fbase = feat + (w * 16 + n16) * 296 + quad * 8; // A: m=lane&15, k=8*quad+j
#pragma unroll
    for (int kt = 0; kt < 9; kt++) {
        bf16x8 a = *(const bf16x8*)(fbase + kt * 32);
        const short* wb = Wp + ((size_t)(kt * 8) * 64 + lane) * 8;
#pragma unroll
        for (int nt = 0; nt < 8; nt++) {
            bf16x8 b = *(const bf16x8*)(wb + (size_t)nt * 64 * 8);
            acc[nt] = __builtin_amdgcn_mfma_f32_16x16x32_bf16(a, b, acc[nt], 0, 0, 0);
        }
    }
#pragma unroll
    for (int nt = 0; nt < 8; nt++) {
        int ch = nt * 16 + n16;
        float bb = bmsg[ch];
#pragma unroll
        for (int r = 0; r < 4; r++) {
            int el = w * 16 + quad * 4 + r; // C/D: row = quad*4 + reg
            atomicAdd(&agg[(size_t)sii[el] * CIN + ch], silu_f(acc[nt][r] + bb));
        }
    }
}

// ---------------- node update: s = s + silu(cat(s, agg) @ Wnode + bnode) (+ bf16 shadow) -------
__global__ void k_node(float* __restrict__ s, short* __restrict__ s_bf, const float* __restrict__ agg,
                       const float* __restrict__ Wnode, const float* __restrict__ bnode)
{
    int n = blockIdx.x, c = threadIdx.x;
    __shared__ float feat[2 * CIN];
    float sold = s[n * CIN + c];
    feat[c] = sold;
    feat[CIN + c] = agg[n * CIN + c];
    __syncthreads();
    float acc = bnode[c];
    for (int d4 = 0; d4 < (2 * CIN) / 4; d4++) {
        float4 f = *(const float4*)&feat[4 * d4];
        acc += f.x * Wnode[(4 * d4 + 0) * CIN + c] + f.y * Wnode[(4 * d4 + 1) * CIN + c]
             + f.z * Wnode[(4 * d4 + 2) * CIN + c] + f.w * Wnode[(4 * d4 + 3) * CIN + c];
    }
    float v = sold + silu_f(acc);
    s[n * CIN + c] = v;
    s_bf[n * CIN + c] = f2bs(v);
}

// ---------------- edge update GEMM (MFMA): e += silu(cat(s[i],s[j],e) @ Wedge + bedge) ---------
__global__ __launch_bounds__(256) void k_edge_mfma(
    const short* __restrict__ s_bf, const short* __restrict__ e_bf_in,
    const int* __restrict__ ii, const int* __restrict__ jj,
    const short* __restrict__ Wp, const float* __restrict__ bedge,
    float* __restrict__ e, short* __restrict__ e_bf)
{
    __shared__ short feat[64 * 296];
    __shared__ int sii[64], sjj[64];
    int tid = threadIdx.x;
    int e0 = blockIdx.x * 64;
    if (tid < 64) sii[tid] = ii[e0 + tid];
    else if (tid < 128) sjj[tid - 64] = jj[e0 + tid - 64];
    __syncthreads();
    for (int idx = tid; idx < 64 * 36; idx += 256) {
        int kl = idx / 36, c = idx - kl * 36;
        uint4 v;
        if (c < 16)      v = ((const uint4*)s_bf)[(size_t)sii[kl] * 16 + c];
        else if (c < 32) v = ((const uint4*)s_bf)[(size_t)sjj[kl] * 16 + (c - 16)];
        else             v = ((const uint4*)e_bf_in)[(size_t)(e0 + kl) * 4 + (c - 32)];
        ((uint4*)feat)[kl * 37 + c] = v;
    }
    __syncthreads();
    int lane = tid & 63, w = tid >> 6;
    int quad = lane >> 4, n16 = lane & 15;
    f32x4 acc[2];
    acc[0] = (f32x4){0.f, 0.f, 0.f, 0.f};
    acc[1] = (f32x4){0.f, 0.f, 0.f, 0.f};
    const short* fbase = feat + (w * 16 + n16) * 296 + quad * 8;
#pragma unroll
    for (int kt = 0; kt < 9; kt++) {
        bf16x8 a = *(const bf16x8*)(fbase + kt * 32);
        const short* wb = Wp + ((size_t)(kt * 2) * 64 + lane) * 8;
        bf16x8 b0 = *(const bf16x8*)(wb);
        bf16x8 b1 = *(const bf16x8*)(wb + (size_t)64 * 8);
        acc[0] = __builtin_amdgcn_mfma_f32_16x16x32_bf16(a, b0, acc[0], 0, 0, 0);
        acc[1] = __builtin_amdgcn_mfma_f32_16x16x32_bf16(a, b1, acc[1], 0, 0, 0);
    }
#pragma unroll
    for (int nt = 0; nt < 2; nt++) {
        int ch = nt * 16 + n16;
        float bb = bedge[ch];
#pragma unroll
        for (int r = 0; r < 4; r++) {
            int el = w * 16 + quad * 4 + r;
            size_t k = (size_t)(e0 + el) * CED + ch;
            float v = e[k] + silu_f(acc[nt][r] + bb);
            e[k] = v;
            e_bf[k] = f2bs(v);
        }
    }
}

// ---------------- post node: s2 = silu(s@Wsh+bsh); al = s2@Wal+bal -----------------------------
__global__ void k_post_node(const float* __restrict__ s,
                            const float* __restrict__ Wsh, const float* __restrict__ bsh,
                            const float* __restrict__ Wal, const float* __restrict__ bal,
                            float* __restrict__ s2, float* __restrict__ out)
{
    int n = blockIdx.x, c = threadIdx.x;
    __shared__ float sh[CIN];
    __shared__ float s2sh[CIN];
    sh[c] = s[n * CIN + c];
    __syncthreads();
    float acc = bsh[c];
    for (int d4 = 0; d4 < CIN / 4; d4++) {
        float4 f = *(const float4*)&sh[4 * d4];
        acc += f.x * Wsh[(4 * d4 + 0) * CIN + c] + f.y * Wsh[(4 * d4 + 1) * CIN + c]
             + f.z * Wsh[(4 * d4 + 2) * CIN + c] + f.w * Wsh[(4 * d4 + 3) * CIN + c];
    }
    float v = silu_f(acc);
    s2[n * CIN + c] = v;
    s2sh[c] = v;
    __syncthreads();
    if (c < CFA + CLAT) {
        float acc2 = bal[c];
        const int AO = CFA + CLAT; // 80
        for (int d4 = 0; d4 < CIN / 4; d4++) {
            float4 f = *(const float4*)&s2sh[4 * d4];
            acc2 += f.x * Wal[(4 * d4 + 0) * AO + c] + f.y * Wal[(4 * d4 + 1) * AO + c]
                  + f.z * Wal[(4 * d4 + 2) * AO + c] + f.w * Wal[(4 * d4 + 3) * AO + c];
        }
        if (c < CFA) out[NN * CLAT + n * CFA + c] = acc2;      // atoms_pred
        else         out[n * CLAT + (c - CFA)] = acc2;         // latent_pred
    }
}

// ---------------- post edge: symmetrize via map, f=silu(s2[i]+s2[j]+e_sym@Wbm+bbm), bonds ------
__global__ void k_post_edge(const float* __restrict__ s2, const float* __restrict__ e,
                            const int* __restrict__ ii, const int* __restrict__ jj, const int* __restrict__ map,
                            const float* __restrict__ Wbm, const float* __restrict__ bbm,
                            const float* __restrict__ Wbl, const float* __restrict__ bbl,
                            float* __restrict__ out)
{
    const int TE = 4;
    int tid = threadIdx.x;
    int e0 = blockIdx.x * TE;
    __shared__ float esym[TE][CED];
    __shared__ float fsh[TE][CIN];
    for (int idx = tid; idx < TE * CED; idx += 128) {
        int le = idx >> 5, d = idx & 31;
        int k = e0 + le;
        int jf = jj[k], ifw = ii[k];
        int kf = map[jf * NN + ifw];
        int kb = map[ifw * NN + jf];
        if (kf < 0) kf = k;
        float v = e[kf * CED + d];
        if (kb >= 0) v += e[kb * CED + d];
        esym[le][d] = 0.5f * v;
    }
    __syncthreads();
    int c = tid;
#pragma unroll
    for (int le = 0; le < TE; le++) {
        int k = e0 + le;
        float acc = bbm[c] + s2[ii[k] * CIN + c] + s2[jj[k] * CIN + c];
        for (int d4 = 0; d4 < CED / 4; d4++) {
            float4 f = *(const float4*)&esym[le][4 * d4];
            acc += f.x * Wbm[(4 * d4 + 0) * CIN + c] + f.y * Wbm[(4 * d4 + 1) * CIN + c]
                 + f.z * Wbm[(4 * d4 + 2) * CIN + c] + f.w * Wbm[(4 * d4 + 3) * CIN + c];
        }
        fsh[le][c] = silu_f(acc);
    }
    __syncthreads();
    if (tid < TE * CNB) {
        int le = tid / CNB, b = tid - le * CNB;
        float acc = bbl[b];
        for (int d = 0; d < CIN; d++) acc += fsh[le][d] * Wbl[d * CNB + b];
        out[NN * CLAT + NN * CFA + (e0 + le) * CNB + b] = acc;
    }
}

extern "C" void kernel_launch(void* const* d_in, const int* in_sizes, int n_in,
                              void* d_out, int out_size, void* d_ws, size_t ws_size,
                              hipStream_t stream) {
    const float* x      = (const float*)d_in[0];
    const float* t      = (const float*)d_in[1];
    const float* z      = (const float*)d_in[2];
    const int*   eidx   = (const int*)d_in[3];
    const int*   jj     = eidx;        // edge_index[0] = j
    const int*   ii     = eidx + NE;   // edge_index[1] = i
    const float* ea     = (const float*)d_in[4];
    const int*   batch  = (const int*)d_in[5];
    const int*   beg    = (const int*)d_in[6];
    const float* Wt_a   = (const float*)d_in[7];
    const float* bt_a   = (const float*)d_in[8];
    const float* Wt_b   = (const float*)d_in[9];
    const float* bt_b   = (const float*)d_in[10];
    const float* W_atom = (const float*)d_in[11];
    const float* b_atom = (const float*)d_in[12];
    const float* W_bond = (const float*)d_in[13];
    const float* b_bond = (const float*)d_in[14];
    const float* W_lat  = (const float*)d_in[15];
    const float* b_lat  = (const float*)d_in[16];
    const float* W_at   = (const float*)d_in[17];
    const float* b_at   = (const float*)d_in[18];
    const float* W_bt   = (const float*)d_in[19];
    const float* b_bt   = (const float*)d_in[20];
    const float* Wmsg   = (const float*)d_in[21];
    const float* bmsg   = (const float*)d_in[22];
    const float* Wnode  = (const float*)d_in[23];
    const float* bnode  = (const float*)d_in[24];
    const float* Wedge  = (const float*)d_in[25];
    const float* bedge  = (const float*)d_in[26];
    const float* Wsh    = (const float*)d_in[27];
    const float* bsh    = (const float*)d_in[28];
    const float* Wbm    = (const float*)d_in[29];
    const float* bbm    = (const float*)d_in[30];
    const float* Wbl    = (const float*)d_in[31];
    const float* bbl    = (const float*)d_in[32];
    const float* Wal    = (const float*)d_in[33];
    const float* bal    = (const float*)d_in[34];

    float* s    = (float*)d_ws;                      // N*128 f32
    float* e    = s + (size_t)NN * CIN;              // E*32 f32
    float* agg  = e + (size_t)NE * CED;              // N*128 f32
    float* s2   = agg + (size_t)NN * CIN;            // N*128 f32
    int*   map  = (int*)(s2 + (size_t)NN * CIN);     // N*N i32
    short* s_bf = (short*)(map + (size_t)NN * NN);   // N*128 bf16
    short* e_bf = s_bf + (size_t)NN * CIN;           // E*32 bf16
    short* Wpm  = e_bf + (size_t)NE * CED;           // 5*9*8*64*8 bf16
    short* Wpe  = Wpm + (size_t)NL * 9 * 8 * 64 * 8; // 5*9*2*64*8 bf16
    float* out  = (float*)d_out;

    hipMemsetAsync(map, 0xFF, (size_t)NN * NN * sizeof(int), stream); // -1
    k_pack_w<<<720, 256, 0, stream>>>(Wmsg, Wedge, Wpm, Wpe);
    k_init_s<<<NN, CIN, 0, stream>>>(x, t, z, batch, Wt_a, bt_a, W_atom, b_atom,
                                     W_lat, b_lat, W_at, b_at, s, s_bf);
    k_init_e<<<NE / 8, 256, 0, stream>>>(ea, t, beg, jj, ii, Wt_b, bt_b, W_bond, b_bond,
                                         W_bt, b_bt, e, e_bf, map);
    for (int l = 0; l < NL; l++) {
        hipMemsetAsync(agg, 0, (size_t)NN * CIN * sizeof(float), stream);
        k_msg_mfma<<<NE / 64, 256, 0, stream>>>(s_bf, e_bf, ii, jj,
                                                Wpm + (size_t)l * 9 * 8 * 64 * 8,
                                                bmsg + l * CIN, agg);
        k_node<<<NN, CIN, 0, stream>>>(s, s_bf, agg, Wnode + (size_t)l * 256 * CIN, bnode + l * CIN);
        k_edge_mfma<<<NE / 64, 256, 0, stream>>>(s_bf, e_bf, ii, jj,
                                                 Wpe + (size_t)l * 9 * 2 * 64 * 8,
                                                 bedge + l * CED, e, e_bf);
    }
    k_post_node<<<NN, CIN, 0, stream>>>(s, Wsh, bsh, Wal, bal, s2, out);
    k_post_edge<<<NE / 4, 128, 0, stream>>>(s2, e, ii, jj, map, Wbm, bbm, Wbl, bbl, out);
}

// Round 4
// 566.418 us; speedup vs baseline: 2.5074x; 1.1104x over previous
//
#include <hip/hip_runtime.h>
#include <hip/hip_bf16.h>

#define NN 2048
#define NE 65536
#define NG 32
#define CIN 128
#define CED 32
#define CLAT 64
#define CFA 16
#define CNB 5
#define NL 5

#define OFF_AT (NN * CLAT)
#define OFF_B  (NN * CLAT + NN * CFA)

typedef __attribute__((ext_vector_type(8))) short bf16x8;
typedef __attribute__((ext_vector_type(4))) float f32x4;

__device__ __forceinline__ float silu_f(float v) { return v / (1.0f + __expf(-v)); }
__device__ __forceinline__ short f2bs(float v) {
    __hip_bfloat16 h = __float2bfloat16(v);
    return *reinterpret_cast<short*>(&h);
}
__device__ __forceinline__ unsigned pack2(float a, float b) {
    return ((unsigned)(unsigned short)f2bs(b) << 16) | (unsigned short)f2bs(a);
}

// ---------------- pack all B-operand weights into MFMA fragment order --------------------------
// layout: [-outer-][nt][lane][8] with k = kt*32 + (lane>>4)*8 + j, n = nt*16 + (lane&15)
__global__ void k_pack_w(const float* __restrict__ Wmsg, const float* __restrict__ Wedge,
                         const float* __restrict__ Wnode, const float* __restrict__ Wsh,
                         const float* __restrict__ Wal, const float* __restrict__ Wbm,
                         short* __restrict__ Wpm, short* __restrict__ Wpe, short* __restrict__ Wpn,
                         short* __restrict__ Wpsh, short* __restrict__ Wpal, short* __restrict__ Wpbm)
{
    int idx = blockIdx.x * 256 + threadIdx.x;
    int j = idx & 7, t0 = idx >> 3, lane = t0 & 63, t = t0 >> 6;
    int kq = (lane >> 4) * 8 + j, n16 = lane & 15;
    if (idx < NL * 9 * 8 * 64 * 8) { // Wmsg: K=288, N=128
        int nt = t & 7, kt = (t >> 3) % 9, l = (t >> 3) / 9;
        Wpm[idx] = f2bs(Wmsg[((size_t)l * 288 + kt * 32 + kq) * CIN + nt * 16 + n16]);
    }
    if (idx < NL * 9 * 2 * 64 * 8) { // Wedge: K=288, N=32
        int nt = t & 1, kt = (t >> 1) % 9, l = (t >> 1) / 9;
        Wpe[idx] = f2bs(Wedge[((size_t)l * 288 + kt * 32 + kq) * CED + nt * 16 + n16]);
    }
    if (idx < NL * 8 * 8 * 64 * 8) { // Wnode: K=256, N=128
        int nt = t & 7, kt = (t >> 3) & 7, l = t >> 6;
        Wpn[idx] = f2bs(Wnode[((size_t)l * 256 + kt * 32 + kq) * CIN + nt * 16 + n16]);
    }
    if (idx < 4 * 8 * 64 * 8) { // Wsh: K=128, N=128
        int nt = t & 7, kt = t >> 3;
        Wpsh[idx] = f2bs(Wsh[(size_t)(kt * 32 + kq) * CIN + nt * 16 + n16]);
    }
    if (idx < 4 * 5 * 64 * 8) { // Wal: K=128, N=80
        int nt = t % 5, kt = t / 5;
        Wpal[idx] = f2bs(Wal[(size_t)(kt * 32 + kq) * 80 + nt * 16 + n16]);
    }
    if (idx < 8 * 64 * 8) { // Wbm: K=32, N=128
        int nt = t & 7;
        Wpbm[idx] = f2bs(Wbm[(size_t)kq * CIN + nt * 16 + n16]);
    }
}

// ---------------- init s: 16 nodes/block, register-blocked GEMV --------------------------------
__global__ __launch_bounds__(128) void k_init_s(
    const float* __restrict__ x, const float* __restrict__ t,
    const float* __restrict__ z, const int* __restrict__ batch,
    const float* __restrict__ Wt_a, const float* __restrict__ bt_a,
    const float* __restrict__ W_atom, const float* __restrict__ b_atom,
    const float* __restrict__ W_lat, const float* __restrict__ b_lat,
    const float* __restrict__ W_at, const float* __restrict__ b_at,
    float* __restrict__ s, short* __restrict__ s_bf)
{
    const int NB = 16;
    int nb0 = blockIdx.x * NB, c = threadIdx.x;
    __shared__ float xs[NB * CFA];    // 1KB
    __shared__ float zs[NB * CLAT];   // 4KB
    __shared__ float tmp[NB * CIN];   // 8KB
    __shared__ float tv[NB];
    if (c < NB * CFA / 4) ((float4*)xs)[c] = ((const float4*)x)[nb0 * (CFA / 4) + c];
    for (int q = c; q < NB * CLAT / 4; q += 128) ((float4*)zs)[q] = ((const float4*)z)[nb0 * (CLAT / 4) + q];
    if (c < NB) tv[c] = t[batch[nb0 + c]];
    __syncthreads();
    float wta = Wt_a[c], base0 = b_atom[c] + bt_a[c];
    float acc[NB];
#pragma unroll
    for (int nd = 0; nd < NB; nd++) acc[nd] = base0 + tv[nd] * wta;
    for (int k = 0; k < CFA; k++) {
        float w = W_atom[k * CIN + c];
#pragma unroll
        for (int nd = 0; nd < NB; nd++) acc[nd] += xs[nd * CFA + k] * w;
    }
#pragma unroll
    for (int nd = 0; nd < NB; nd++) tmp[nd * CIN + c] = acc[nd];
    __syncthreads();
    float base1 = b_at[c] + b_lat[c];
    float acc2[NB];
#pragma unroll
    for (int nd = 0; nd < NB; nd++) acc2[nd] = base1;
    for (int k4 = 0; k4 < CIN / 4; k4++) {
        float w0 = W_at[(4 * k4 + 0) * CIN + c], w1 = W_at[(4 * k4 + 1) * CIN + c];
        float w2 = W_at[(4 * k4 + 2) * CIN + c], w3 = W_at[(4 * k4 + 3) * CIN + c];
#pragma unroll
        for (int nd = 0; nd < NB; nd++) {
            float4 f = *(const float4*)&tmp[nd * CIN + 4 * k4];
            acc2[nd] += f.x * w0 + f.y * w1 + f.z * w2 + f.w * w3;
        }
    }
    for (int k4 = 0; k4 < CLAT / 4; k4++) {
        float w0 = W_lat[(4 * k4 + 0) * CIN + c], w1 = W_lat[(4 * k4 + 1) * CIN + c];
        float w2 = W_lat[(4 * k4 + 2) * CIN + c], w3 = W_lat[(4 * k4 + 3) * CIN + c];
#pragma unroll
        for (int nd = 0; nd < NB; nd++) {
            float4 f = *(const float4*)&zs[nd * CLAT + 4 * k4];
            acc2[nd] += f.x * w0 + f.y * w1 + f.z * w2 + f.w * w3;
        }
    }
#pragma unroll
    for (int nd = 0; nd < NB; nd++) {
        s[(nb0 + nd) * CIN + c] = acc2[nd];
        s_bf[(nb0 + nd) * CIN + c] = f2bs(acc2[nd]);
    }
}

// ---------------- init e (+ bf16 shadow) + dense map scatter -----------------------------------
__global__ void k_init_e(const float* __restrict__ ea, const float* __restrict__ t,
                         const int* __restrict__ beg, const int* __restrict__ jj, const int* __restrict__ ii,
                         const float* __restrict__ Wt_b, const float* __restrict__ bt_b,
                         const float* __restrict__ W_bond, const float* __restrict__ b_bond,
                         const float* __restrict__ W_bt, const float* __restrict__ b_bt,
                         float* __restrict__ e, short* __restrict__ e_bf, int* __restrict__ map)
{
    int le = threadIdx.x >> 5, c = threadIdx.x & 31;
    int k = blockIdx.x * 8 + le;
    __shared__ float tmp[8][CED];
    float tg = t[beg[k]];
    float acc = b_bond[c] + tg * Wt_b[c] + bt_b[c];
#pragma unroll
    for (int b = 0; b < CNB; b++) acc += ea[k * CNB + b] * W_bond[b * CED + c];
    tmp[le][c] = acc;
    __syncthreads();
    float acc2 = b_bt[c];
#pragma unroll
    for (int d = 0; d < CED; d++) acc2 += tmp[le][d] * W_bt[d * CED + c];
    e[k * CED + c] = acc2;
    e_bf[k * CED + c] = f2bs(acc2);
    if (c == 0) atomicMax(&map[jj[k] * NN + ii[k]], k);
}

// ---------------- msg GEMM (MFMA) + fused segment_sum ------------------------------------------
__global__ __launch_bounds__(256) void k_msg_mfma(
    const short* __restrict__ s_bf, const short* __restrict__ e_bf,
    const int* __restrict__ ii, const int* __restrict__ jj,
    const short* __restrict__ Wp, const float* __restrict__ bmsg,
    float* __restrict__ agg)
{
    __shared__ short feat[64 * 296];
    __shared__ int sii[64], sjj[64];
    int tid = threadIdx.x;
    int e0 = blockIdx.x * 64;
    if (tid < 64) sii[tid] = ii[e0 + tid];
    else if (tid < 128) sjj[tid - 64] = jj[e0 + tid - 64];
    __syncthreads();
    for (int idx = tid; idx < 64 * 36; idx += 256) {
        int kl = idx / 36, c = idx - kl * 36;
        uint4 v;
        if (c < 16)      v = ((const uint4*)s_bf)[(size_t)sii[kl] * 16 + c];
        else if (c < 32) v = ((const uint4*)s_bf)[(size_t)sjj[kl] * 16 + (c - 16)];
        else             v = ((const uint4*)e_bf)[(size_t)(e0 + kl) * 4 + (c - 32)];
        ((uint4*)feat)[kl * 37 + c] = v;
    }
    __syncthreads();
    int lane = tid & 63, w = tid >> 6;
    int quad = lane >> 4, n16 = lane & 15;
    f32x4 acc[8];
#pragma unroll
    for (int t2 = 0; t2 < 8; t2++) acc[t2] = (f32x4){0.f, 0.f, 0.f, 0.f};
    const short* fbase = feat + (w * 16 + n16) * 296 + quad * 8;
#pragma unroll
    for (int kt = 0; kt < 9; kt++) {
        bf16x8 a = *(const bf16x8*)(fbase + kt * 32);
        const short* wb = Wp + ((size_t)(kt * 8) * 64 + lane) * 8;
#pragma unroll
        for (int nt = 0; nt < 8; nt++) {
            bf16x8 b = *(const bf16x8*)(wb + (size_t)nt * 64 * 8);
            acc[nt] = __builtin_amdgcn_mfma_f32_16x16x32_bf16(a, b, acc[nt], 0, 0, 0);
        }
    }
#pragma unroll
    for (int nt = 0; nt < 8; nt++) {
        int ch = nt * 16 + n16;
        float bb = bmsg[ch];
#pragma unroll
        for (int r = 0; r < 4; r++) {
            int el = w * 16 + quad * 4 + r;
            atomicAdd(&agg[(size_t)sii[el] * CIN + ch], silu_f(acc[nt][r] + bb));
        }
    }
}

// ---------------- node update (MFMA): s += silu(cat(s,agg) @ Wnode + bnode), 64 nodes/block ----
__global__ __launch_bounds__(256) void k_node_mfma(
    float* __restrict__ s, short* __restrict__ s_bf, const float* __restrict__ agg,
    const short* __restrict__ Wp, const float* __restrict__ bnode)
{
    __shared__ short feat[64 * 264]; // 64 rows of K=256 bf16, padded to 264
    int tid = threadIdx.x;
    int nb0 = blockIdx.x * 64;
    for (int idx = tid; idx < 64 * 16; idx += 256)  // s_bf rows (k 0..127)
        ((uint4*)feat)[(idx >> 4) * 33 + (idx & 15)] = ((const uint4*)s_bf)[(size_t)nb0 * 16 + idx];
    for (int idx = tid; idx < 64 * 32; idx += 256) { // agg fp32 -> bf16 (k 128..255)
        int kl = idx >> 5, c = idx & 31;
        float4 v = ((const float4*)agg)[(size_t)(nb0 + kl) * 32 + c];
        uint2 p; p.x = pack2(v.x, v.y); p.y = pack2(v.z, v.w);
        *(uint2*)&feat[kl * 264 + 128 + 4 * c] = p;
    }
    __syncthreads();
    int lane = tid & 63, w = tid >> 6;
    int quad = lane >> 4, n16 = lane & 15;
    f32x4 acc[8];
#pragma unroll
    for (int t2 = 0; t2 < 8; t2++) acc[t2] = (f32x4){0.f, 0.f, 0.f, 0.f};
    const short* fbase = feat + (w * 16 + n16) * 264 + quad * 8;
#pragma unroll
    for (int kt = 0; kt < 8; kt++) {
        bf16x8 a = *(const bf16x8*)(fbase + kt * 32);
        const short* wb = Wp + ((size_t)(kt * 8) * 64 + lane) * 8;
#pragma unroll
        for (int nt = 0; nt < 8; nt++) {
            bf16x8 b = *(const bf16x8*)(wb + (size_t)nt * 64 * 8);
            acc[nt] = __builtin_amdgcn_mfma_f32_16x16x32_bf16(a, b, acc[nt], 0, 0, 0);
        }
    }
#pragma unroll
    for (int nt = 0; nt < 8; nt++) {
        int col = nt * 16 + n16;
        float bb = bnode[col];
#pragma unroll
        for (int r = 0; r < 4; r++) {
            int node = nb0 + w * 16 + quad * 4 + r;
            size_t ix = (size_t)node * CIN + col;
            float v = s[ix] + silu_f(acc[nt][r] + bb);
            s[ix] = v;
            s_bf[ix] = f2bs(v);
        }
    }
}

// ---------------- edge update GEMM (MFMA) ------------------------------------------------------
__global__ __launch_bounds__(256) void k_edge_mfma(
    const short* __restrict__ s_bf, const short* __restrict__ e_bf_in,
    const int* __restrict__ ii, const int* __restrict__ jj,
    const short* __restrict__ Wp, const float* __restrict__ bedge,
    float* __restrict__ e, short* __restrict__ e_bf)
{
    __shared__ short feat[64 * 296];
    __shared__ int sii[64], sjj[64];
    int tid = threadIdx.x;
    int e0 = blockIdx.x * 64;
    if (tid < 64) sii[tid] = ii[e0 + tid];
    else if (tid < 128) sjj[tid - 64] = jj[e0 + tid - 64];
    __syncthreads();
    for (int idx = tid; idx < 64 * 36; idx += 256) {
        int kl = idx / 36, c = idx - kl * 36;
        uint4 v;
        if (c < 16)      v = ((const uint4*)s_bf)[(size_t)sii[kl] * 16 + c];
        else if (c < 32) v = ((const uint4*)s_bf)[(size_t)sjj[kl] * 16 + (c - 16)];
        else             v = ((const uint4*)e_bf_in)[(size_t)(e0 + kl) * 4 + (c - 32)];
        ((uint4*)feat)[kl * 37 + c] = v;
    }
    __syncthreads();
    int lane = tid & 63, w = tid >> 6;
    int quad = lane >> 4, n16 = lane & 15;
    f32x4 acc[2];
    acc[0] = (f32x4){0.f, 0.f, 0.f, 0.f};
    acc[1] = (f32x4){0.f, 0.f, 0.f, 0.f};
    const short* fbase = feat + (w * 16 + n16) * 296 + quad * 8;
#pragma unroll
    for (int kt = 0; kt < 9; kt++) {
        bf16x8 a = *(const bf16x8*)(fbase + kt * 32);
        const short* wb = Wp + ((size_t)(kt * 2) * 64 + lane) * 8;
        bf16x8 b0 = *(const bf16x8*)(wb);
        bf16x8 b1 = *(const bf16x8*)(wb + (size_t)64 * 8);
        acc[0] = __builtin_amdgcn_mfma_f32_16x16x32_bf16(a, b0, acc[0], 0, 0, 0);
        acc[1] = __builtin_amdgcn_mfma_f32_16x16x32_bf16(a, b1, acc[1], 0, 0, 0);
    }
#pragma unroll
    for (int nt = 0; nt < 2; nt++) {
        int ch = nt * 16 + n16;
        float bb = bedge[ch];
#pragma unroll
        for (int r = 0; r < 4; r++) {
            int el = w * 16 + quad * 4 + r;
            size_t k = (size_t)(e0 + el) * CED + ch;
            float v = e[k] + silu_f(acc[nt][r] + bb);
            e[k] = v;
            e_bf[k] = f2bs(v);
        }
    }
}

// ---------------- post node (MFMA, chained): s2 = silu(s@Wsh+bsh); al = s2@Wal+bal -------------
__global__ __launch_bounds__(256) void k_post_node_mfma(
    const short* __restrict__ s_bf,
    const short* __restrict__ Wpsh, const float* __restrict__ bsh,
    const short* __restrict__ Wpal, const float* __restrict__ bal,
    float* __restrict__ s2, float* __restrict__ out)
{
    __shared__ short feat[64 * 136];
    int tid = threadIdx.x;
    int nb0 = blockIdx.x * 64;
    for (int idx = tid; idx < 64 * 16; idx += 256)
        ((uint4*)feat)[(idx >> 4) * 17 + (idx & 15)] = ((const uint4*)s_bf)[(size_t)nb0 * 16 + idx];
    __syncthreads();
    int lane = tid & 63, w = tid >> 6;
    int quad = lane >> 4, n16 = lane & 15;
    f32x4 acc[8];
#pragma unroll
    for (int t2 = 0; t2 < 8; t2++) acc[t2] = (f32x4){0.f, 0.f, 0.f, 0.f};
    const short* fbase = feat + (w * 16 + n16) * 136 + quad * 8;
#pragma unroll
    for (int kt = 0; kt < 4; kt++) {
        bf16x8 a = *(const bf16x8*)(fbase + kt * 32);
        const short* wb = Wpsh + ((size_t)(kt * 8) * 64 + lane) * 8;
#pragma unroll
        for (int nt = 0; nt < 8; nt++) {
            bf16x8 b = *(const bf16x8*)(wb + (size_t)nt * 64 * 8);
            acc[nt] = __builtin_amdgcn_mfma_f32_16x16x32_bf16(a, b, acc[nt], 0, 0, 0);
        }
    }
    // epilogue 1: silu -> s2 global (fp32) + own-wave LDS tile (bf16) for GEMM2 (no barrier:
    // each wave reads/writes only its own 16 rows)
#pragma unroll
    for (int nt = 0; nt < 8; nt++) {
        int col = nt * 16 + n16;
        float bb = bsh[col];
#pragma unroll
        for (int r = 0; r < 4; r++) {
            int row = quad * 4 + r;
            float v = silu_f(acc[nt][r] + bb);
            s2[(size_t)(nb0 + w * 16 + row) * CIN + col] = v;
            feat[(w * 16 + row) * 136 + col] = f2bs(v);
        }
    }
    f32x4 acc2[5];
#pragma unroll
    for (int t2 = 0; t2 < 5; t2++) acc2[t2] = (f32x4){0.f, 0.f, 0.f, 0.f};
#pragma unroll
    for (int kt = 0; kt < 4; kt++) {
        bf16x8 a = *(const bf16x8*)(fbase + kt * 32);
        const short* wb = Wpal + ((size_t)(kt * 5) * 64 + lane) * 8;
#pragma unroll
        for (int nt = 0; nt < 5; nt++) {
            bf16x8 b = *(const bf16x8*)(wb + (size_t)nt * 64 * 8);
            acc2[nt] = __builtin_amdgcn_mfma_f32_16x16x32_bf16(a, b, acc2[nt], 0, 0, 0);
        }
    }
#pragma unroll
    for (int nt = 0; nt < 5; nt++) {
        int col = nt * 16 + n16;
        float bb = bal[col];
#pragma unroll
        for (int r = 0; r < 4; r++) {
            int node = nb0 + w * 16 + quad * 4 + r;
            float v = acc2[nt][r] + bb;
            if (col < CFA) out[OFF_AT + node * CFA + col] = v;
            else           out[(size_t)node * CLAT + (col - CFA)] = v;
        }
    }
}

// ---------------- post edge (MFMA): esym@Wbm GEMM + silu + Wbl tail, 64 edges/block ------------
__global__ __launch_bounds__(256) void k_post_edge_mfma(
    const float* __restrict__ s2, const float* __restrict__ e,
    const int* __restrict__ ii, const int* __restrict__ jj, const int* __restrict__ map,
    const short* __restrict__ Wpbm, const float* __restrict__ bbm,
    const float* __restrict__ Wbl, const float* __restrict__ bbl,
    float* __restrict__ out)
{
    __shared__ int sii[64], sjj[64], skf[64], skb[64];
    __shared__ short esym[64 * 40];   // rows: 32 bf16 used, pad 40
    __shared__ float sbias[64 * 132]; // s2[i]+s2[j]; later aliased as fshT[128][66]
    int tid = threadIdx.x;
    int e0 = blockIdx.x * 64;
    if (tid < 64) sii[tid] = ii[e0 + tid];
    else if (tid < 128) sjj[tid - 64] = jj[e0 + tid - 64];
    __syncthreads();
    if (tid < 64) skf[tid] = map[(size_t)sjj[tid] * NN + sii[tid]];
    else if (tid < 128) skb[tid - 64] = map[(size_t)sii[tid - 64] * NN + sjj[tid - 64]];
    __syncthreads();
    for (int idx = tid; idx < 64 * 8; idx += 256) { // esym rows: 8 chunks of 4 floats
        int kl = idx >> 3, c = idx & 7;
        float4 a = ((const float4*)e)[(size_t)skf[kl] * 8 + c];
        int kb = skb[kl];
        float4 b = {0.f, 0.f, 0.f, 0.f};
        if (kb >= 0) b = ((const float4*)e)[(size_t)kb * 8 + c];
        uint2 p; p.x = pack2(0.5f * (a.x + b.x), 0.5f * (a.y + b.y));
        p.y = pack2(0.5f * (a.z + b.z), 0.5f * (a.w + b.w));
        *(uint2*)&esym[kl * 40 + 4 * c] = p;
    }
    for (int idx = tid; idx < 64 * 32; idx += 256) { // sbias rows: s2[i]+s2[j]
        int kl = idx >> 5, c = idx & 31;
        float4 a = ((const float4*)s2)[(size_t)sii[kl] * 32 + c];
        float4 b = ((const float4*)s2)[(size_t)sjj[kl] * 32 + c];
        float4 v = {a.x + b.x, a.y + b.y, a.z + b.z, a.w + b.w};
        *(float4*)&sbias[kl * 132 + 4 * c] = v;
    }
    __syncthreads();
    int lane = tid & 63, w = tid >> 6;
    int quad = lane >> 4, n16 = lane & 15;
    bf16x8 a = *(const bf16x8*)(esym + (w * 16 + n16) * 40 + quad * 8);
    f32x4 acc[8];
#pragma unroll
    for (int nt = 0; nt < 8; nt++) {
        bf16x8 b = *(const bf16x8*)(Wpbm + ((size_t)nt * 64 + lane) * 8);
        f32x4 zero = {0.f, 0.f, 0.f, 0.f};
        acc[nt] = __builtin_amdgcn_mfma_f32_16x16x32_bf16(a, b, zero, 0, 0, 0);
    }
    float f[8][4];
#pragma unroll
    for (int nt = 0; nt < 8; nt++) {
        int col = nt * 16 + n16;
        float bb = bbm[col];
#pragma unroll
        for (int r = 0; r < 4; r++) {
            int row = w * 16 + quad * 4 + r;
            f[nt][r] = silu_f(acc[nt][r] + bb + sbias[row * 132 + col]);
        }
    }
    __syncthreads(); // all sbias reads done before alias overwrite
    float* fshT = sbias; // [128][66]
#pragma unroll
    for (int nt = 0; nt < 8; nt++) {
        int col = nt * 16 + n16;
#pragma unroll
        for (int r = 0; r < 4; r++) {
            int row = w * 16 + quad * 4 + r;
            fshT[col * 66 + row] = f[nt][r];
        }
    }
    __syncthreads();
    for (int idx = tid; idx < 64 * CNB; idx += 256) {
        int kl = idx / CNB, b = idx - kl * CNB;
        float acc3 = bbl[b];
        for (int d = 0; d < CIN; d++) acc3 += fshT[d * 66 + kl] * Wbl[d * CNB + b];
        out[OFF_B + (size_t)(e0 + kl) * CNB + b] = acc3;
    }
}

extern "C" void kernel_launch(void* const* d_in, const int* in_sizes, int n_in,
                              void* d_out, int out_size, void* d_ws, size_t ws_size,
                              hipStream_t stream) {
    const float* x      = (const float*)d_in[0];
    const float* t      = (const float*)d_in[1];
    const float* z      = (const float*)d_in[2];
    const int*   eidx   = (const int*)d_in[3];
    const int*   jj     = eidx;        // edge_index[0] = j
    const int*   ii     = eidx + NE;   // edge_index[1] = i
    const float* ea     = (const float*)d_in[4];
    const int*   batch  = (const int*)d_in[5];
    const int*   beg    = (const int*)d_in[6];
    const float* Wt_a   = (const float*)d_in[7];
    const float* bt_a   = (const float*)d_in[8];
    const float* Wt_b   = (const float*)d_in[9];
    const float* bt_b   = (const float*)d_in[10];
    const float* W_atom = (const float*)d_in[11];
    const float* b_atom = (const float*)d_in[12];
    const float* W_bond = (const float*)d_in[13];
    const float* b_bond = (const float*)d_in[14];
    const float* W_lat  = (const float*)d_in[15];
    const float* b_lat  = (const float*)d_in[16];
    const float* W_at   = (const float*)d_in[17];
    const float* b_at   = (const float*)d_in[18];
    const float* W_bt   = (const float*)d_in[19];
    const float* b_bt   = (const float*)d_in[20];
    const float* Wmsg   = (const float*)d_in[21];
    const float* bmsg   = (const float*)d_in[22];
    const float* Wnode  = (const float*)d_in[23];
    const float* bnode  = (const float*)d_in[24];
    const float* Wedge  = (const float*)d_in[25];
    const float* bedge  = (const float*)d_in[26];
    const float* Wsh    = (const float*)d_in[27];
    const float* bsh    = (const float*)d_in[28];
    const float* Wbm    = (const float*)d_in[29];
    const float* bbm    = (const float*)d_in[30];
    const float* Wbl    = (const float*)d_in[31];
    const float* bbl    = (const float*)d_in[32];
    const float* Wal    = (const float*)d_in[33];
    const float* bal    = (const float*)d_in[34];

    float* s    = (float*)d_ws;                        // N*128 f32
    float* e    = s + (size_t)NN * CIN;                // E*32 f32
    float* agg  = e + (size_t)NE * CED;                // N*128 f32
    float* s2   = agg + (size_t)NN * CIN;              // N*128 f32
    int*   map  = (int*)(s2 + (size_t)NN * CIN);       // N*N i32
    short* s_bf = (short*)(map + (size_t)NN * NN);     // N*128 bf16
    short* e_bf = s_bf + (size_t)NN * CIN;             // E*32 bf16
    short* Wpm  = e_bf + (size_t)NE * CED;             // 184320
    short* Wpe  = Wpm + (size_t)NL * 9 * 8 * 64 * 8;   // 46080
    short* Wpn  = Wpe + (size_t)NL * 9 * 2 * 64 * 8;   // 163840
    short* Wpsh = Wpn + (size_t)NL * 8 * 8 * 64 * 8;   // 16384
    short* Wpal = Wpsh + (size_t)4 * 8 * 64 * 8;       // 10240
    short* Wpbm = Wpal + (size_t)4 * 5 * 64 * 8;       // 4096
    float* out  = (float*)d_out;

    hipMemsetAsync(map, 0xFF, (size_t)NN * NN * sizeof(int), stream); // -1
    k_pack_w<<<720, 256, 0, stream>>>(Wmsg, Wedge, Wnode, Wsh, Wal, Wbm,
                                      Wpm, Wpe, Wpn, Wpsh, Wpal, Wpbm);
    k_init_s<<<NN / 16, 128, 0, stream>>>(x, t, z, batch, Wt_a, bt_a, W_atom, b_atom,
                                          W_lat, b_lat, W_at, b_at, s, s_bf);
    k_init_e<<<NE / 8, 256, 0, stream>>>(ea, t, beg, jj, ii, Wt_b, bt_b, W_bond, b_bond,
                                         W_bt, b_bt, e, e_bf, map);
    for (int l = 0; l < NL; l++) {
        hipMemsetAsync(agg, 0, (size_t)NN * CIN * sizeof(float), stream);
        k_msg_mfma<<<NE / 64, 256, 0, stream>>>(s_bf, e_bf, ii, jj,
                                                Wpm + (size_t)l * 9 * 8 * 64 * 8,
                                                bmsg + l * CIN, agg);
        k_node_mfma<<<NN / 64, 256, 0, stream>>>(s, s_bf, agg,
                                                 Wpn + (size_t)l * 8 * 8 * 64 * 8,
                                                 bnode + l * CIN);
        k_edge_mfma<<<NE / 64, 256, 0, stream>>>(s_bf, e_bf, ii, jj,
                                                 Wpe + (size_t)l * 9 * 2 * 64 * 8,
                                                 bedge + l * CED, e, e_bf);
    }
    k_post_node_mfma<<<NN / 64, 256, 0, stream>>>(s_bf, Wpsh, bsh, Wpal, bal, s2, out);
    k_post_edge_mfma<<<NE / 64, 256, 0, stream>>>(s2, e, ii, jj, map, Wpbm, bbm, Wbl, bbl, out);
}

// Round 5
// 528.488 us; speedup vs baseline: 2.6874x; 1.0718x over previous
//
#include <hip/hip_runtime.h>
#include <hip/hip_bf16.h>

#define NN 2048
#define NE 65536
#define NG 32
#define CIN 128
#define CED 32
#define CLAT 64
#define CFA 16
#define CNB 5
#define NL 5

#define OFF_AT (NN * CLAT)
#define OFF_B  (NN * CLAT + NN * CFA)

typedef __attribute__((ext_vector_type(8))) short bf16x8;
typedef __attribute__((ext_vector_type(4))) float f32x4;

__device__ __forceinline__ float silu_f(float v) { return v / (1.0f + __expf(-v)); }
__device__ __forceinline__ short f2bs(float v) {
    __hip_bfloat16 h = __float2bfloat16(v);
    return *reinterpret_cast<short*>(&h);
}
__device__ __forceinline__ unsigned pack2(float a, float b) {
    return ((unsigned)(unsigned short)f2bs(b) << 16) | (unsigned short)f2bs(a);
}

// ---------------- pack all B-operand weights into MFMA fragment order --------------------------
__global__ void k_pack_w(const float* __restrict__ Wmsg, const float* __restrict__ Wedge,
                         const float* __restrict__ Wnode, const float* __restrict__ Wsh,
                         const float* __restrict__ Wal, const float* __restrict__ Wbm,
                         short* __restrict__ Wpm, short* __restrict__ Wpe, short* __restrict__ Wpn,
                         short* __restrict__ Wpsh, short* __restrict__ Wpal, short* __restrict__ Wpbm)
{
    int idx = blockIdx.x * 256 + threadIdx.x;
    int j = idx & 7, t0 = idx >> 3, lane = t0 & 63, t = t0 >> 6;
    int kq = (lane >> 4) * 8 + j, n16 = lane & 15;
    if (idx < NL * 9 * 8 * 64 * 8) { // Wmsg: K=288, N=128
        int nt = t & 7, kt = (t >> 3) % 9, l = (t >> 3) / 9;
        Wpm[idx] = f2bs(Wmsg[((size_t)l * 288 + kt * 32 + kq) * CIN + nt * 16 + n16]);
    }
    if (idx < NL * 9 * 2 * 64 * 8) { // Wedge: K=288, N=32
        int nt = t & 1, kt = (t >> 1) % 9, l = (t >> 1) / 9;
        Wpe[idx] = f2bs(Wedge[((size_t)l * 288 + kt * 32 + kq) * CED + nt * 16 + n16]);
    }
    if (idx < NL * 8 * 8 * 64 * 8) { // Wnode: K=256, N=128
        int nt = t & 7, kt = (t >> 3) & 7, l = t >> 6;
        Wpn[idx] = f2bs(Wnode[((size_t)l * 256 + kt * 32 + kq) * CIN + nt * 16 + n16]);
    }
    if (idx < 4 * 8 * 64 * 8) { // Wsh: K=128, N=128
        int nt = t & 7, kt = t >> 3;
        Wpsh[idx] = f2bs(Wsh[(size_t)(kt * 32 + kq) * CIN + nt * 16 + n16]);
    }
    if (idx < 4 * 5 * 64 * 8) { // Wal: K=128, N=80
        int nt = t % 5, kt = t / 5;
        Wpal[idx] = f2bs(Wal[(size_t)(kt * 32 + kq) * 80 + nt * 16 + n16]);
    }
    if (idx < 8 * 64 * 8) { // Wbm: K=32, N=128
        int nt = t & 7;
        Wpbm[idx] = f2bs(Wbm[(size_t)kq * CIN + nt * 16 + n16]);
    }
}

// ---------------- init s: 16 nodes/block, register-blocked GEMV --------------------------------
__global__ __launch_bounds__(128) void k_init_s(
    const float* __restrict__ x, const float* __restrict__ t,
    const float* __restrict__ z, const int* __restrict__ batch,
    const float* __restrict__ Wt_a, const float* __restrict__ bt_a,
    const float* __restrict__ W_atom, const float* __restrict__ b_atom,
    const float* __restrict__ W_lat, const float* __restrict__ b_lat,
    const float* __restrict__ W_at, const float* __restrict__ b_at,
    float* __restrict__ s, short* __restrict__ s_bf)
{
    const int NB = 16;
    int nb0 = blockIdx.x * NB, c = threadIdx.x;
    __shared__ float xs[NB * CFA];
    __shared__ float zs[NB * CLAT];
    __shared__ float tmp[NB * CIN];
    __shared__ float tv[NB];
    if (c < NB * CFA / 4) ((float4*)xs)[c] = ((const float4*)x)[nb0 * (CFA / 4) + c];
    for (int q = c; q < NB * CLAT / 4; q += 128) ((float4*)zs)[q] = ((const float4*)z)[nb0 * (CLAT / 4) + q];
    if (c < NB) tv[c] = t[batch[nb0 + c]];
    __syncthreads();
    float wta = Wt_a[c], base0 = b_atom[c] + bt_a[c];
    float acc[NB];
#pragma unroll
    for (int nd = 0; nd < NB; nd++) acc[nd] = base0 + tv[nd] * wta;
    for (int k = 0; k < CFA; k++) {
        float w = W_atom[k * CIN + c];
#pragma unroll
        for (int nd = 0; nd < NB; nd++) acc[nd] += xs[nd * CFA + k] * w;
    }
#pragma unroll
    for (int nd = 0; nd < NB; nd++) tmp[nd * CIN + c] = acc[nd];
    __syncthreads();
    float base1 = b_at[c] + b_lat[c];
    float acc2[NB];
#pragma unroll
    for (int nd = 0; nd < NB; nd++) acc2[nd] = base1;
    for (int k4 = 0; k4 < CIN / 4; k4++) {
        float w0 = W_at[(4 * k4 + 0) * CIN + c], w1 = W_at[(4 * k4 + 1) * CIN + c];
        float w2 = W_at[(4 * k4 + 2) * CIN + c], w3 = W_at[(4 * k4 + 3) * CIN + c];
#pragma unroll
        for (int nd = 0; nd < NB; nd++) {
            float4 f = *(const float4*)&tmp[nd * CIN + 4 * k4];
            acc2[nd] += f.x * w0 + f.y * w1 + f.z * w2 + f.w * w3;
        }
    }
    for (int k4 = 0; k4 < CLAT / 4; k4++) {
        float w0 = W_lat[(4 * k4 + 0) * CIN + c], w1 = W_lat[(4 * k4 + 1) * CIN + c];
        float w2 = W_lat[(4 * k4 + 2) * CIN + c], w3 = W_lat[(4 * k4 + 3) * CIN + c];
#pragma unroll
        for (int nd = 0; nd < NB; nd++) {
            float4 f = *(const float4*)&zs[nd * CLAT + 4 * k4];
            acc2[nd] += f.x * w0 + f.y * w1 + f.z * w2 + f.w * w3;
        }
    }
#pragma unroll
    for (int nd = 0; nd < NB; nd++) {
        s[(nb0 + nd) * CIN + c] = acc2[nd];
        s_bf[(nb0 + nd) * CIN + c] = f2bs(acc2[nd]);
    }
}

// ---------------- init e (+bf16 shadow) + map scatter + degree count ---------------------------
__global__ void k_init_e(const float* __restrict__ ea, const float* __restrict__ t,
                         const int* __restrict__ beg, const int* __restrict__ jj, const int* __restrict__ ii,
                         const float* __restrict__ Wt_b, const float* __restrict__ bt_b,
                         const float* __restrict__ W_bond, const float* __restrict__ b_bond,
                         const float* __restrict__ W_bt, const float* __restrict__ b_bt,
                         float* __restrict__ e, short* __restrict__ e_bf, int* __restrict__ map,
                         int* __restrict__ cnt)
{
    int le = threadIdx.x >> 5, c = threadIdx.x & 31;
    int k = blockIdx.x * 8 + le;
    __shared__ float tmp[8][CED];
    float tg = t[beg[k]];
    float acc = b_bond[c] + tg * Wt_b[c] + bt_b[c];
#pragma unroll
    for (int b = 0; b < CNB; b++) acc += ea[k * CNB + b] * W_bond[b * CED + c];
    tmp[le][c] = acc;
    __syncthreads();
    float acc2 = b_bt[c];
#pragma unroll
    for (int d = 0; d < CED; d++) acc2 += tmp[le][d] * W_bt[d * CED + c];
    e[k * CED + c] = acc2;
    e_bf[k * CED + c] = f2bs(acc2);
    if (c == 0) {
        atomicMax(&map[jj[k] * NN + ii[k]], k);
        atomicAdd(&cnt[ii[k]], 1);
    }
}

// ---------------- prefix sum over cnt[2048] -> rowpos (exclusive) ------------------------------
__global__ __launch_bounds__(256) void k_prefix(const int* __restrict__ cnt, int* __restrict__ rowpos)
{
    __shared__ int part[256];
    int tid = threadIdx.x;
    int loc[8], sum = 0;
#pragma unroll
    for (int q = 0; q < 8; q++) { loc[q] = cnt[tid * 8 + q]; sum += loc[q]; }
    part[tid] = sum;
    __syncthreads();
    if (tid == 0) {
        int r = 0;
        for (int i = 0; i < 256; i++) { int v = part[i]; part[i] = r; r += v; }
    }
    __syncthreads();
    int r = part[tid];
#pragma unroll
    for (int q = 0; q < 8; q++) { rowpos[tid * 8 + q] = r; r += loc[q]; }
}

// ---------------- build perm: edges sorted by target i -----------------------------------------
__global__ void k_perm(const int* __restrict__ ii, int* __restrict__ rowpos, int* __restrict__ perm)
{
    int k = blockIdx.x * 256 + threadIdx.x;
    if (k < NE) {
        int p = atomicAdd(&rowpos[ii[k]], 1);
        perm[p] = k;
    }
}

// ---------------- fused [edge_l -> msg_{l+1}] on sorted edges, pre-aggregated segment sum ------
// DO_EDGE: e += silu(feat @ Wedge); patches e-section of LDS feat.
// DO_MSG : m = silu(feat @ Wmsg); per-block group-reduce by sorted target; few atomics.
template<bool DO_EDGE, bool DO_MSG>
__global__ __launch_bounds__(256) void k_fused(
    const short* __restrict__ s_bf, const short* __restrict__ e_bf_in,
    const int* __restrict__ ii, const int* __restrict__ jj, const int* __restrict__ perm,
    const short* __restrict__ WpE, const float* __restrict__ bedge,
    float* __restrict__ e, short* __restrict__ e_bf,
    const short* __restrict__ WpM, const float* __restrict__ bmsg,
    float* __restrict__ agg)
{
    __shared__ short feat[64 * 296]; // bf16 tile; later low 32KB aliased as fp32 msg values
    __shared__ int sii[64], sjj[64], sek[64];
    int tid = threadIdx.x;
    int e0 = blockIdx.x * 64;
    if (tid < 64) {
        int k = perm[e0 + tid];
        sek[tid] = k;
        sii[tid] = ii[k];   // sorted non-decreasing across tid
        sjj[tid] = jj[k];
    }
    __syncthreads();
    for (int idx = tid; idx < 64 * 36; idx += 256) {
        int kl = idx / 36, c = idx - kl * 36;
        uint4 v;
        if (c < 16)      v = ((const uint4*)s_bf)[(size_t)sii[kl] * 16 + c];
        else if (c < 32) v = ((const uint4*)s_bf)[(size_t)sjj[kl] * 16 + (c - 16)];
        else             v = ((const uint4*)e_bf_in)[(size_t)sek[kl] * 4 + (c - 32)];
        ((uint4*)feat)[kl * 37 + c] = v;
    }
    __syncthreads();
    int lane = tid & 63, w = tid >> 6;
    int quad = lane >> 4, n16 = lane & 15;
    const short* fbase = feat + (w * 16 + n16) * 296 + quad * 8;

    if (DO_EDGE) {
        f32x4 acc[2];
        acc[0] = (f32x4){0.f, 0.f, 0.f, 0.f};
        acc[1] = (f32x4){0.f, 0.f, 0.f, 0.f};
#pragma unroll
        for (int kt = 0; kt < 9; kt++) {
            bf16x8 a = *(const bf16x8*)(fbase + kt * 32);
            const short* wb = WpE + ((size_t)(kt * 2) * 64 + lane) * 8;
            bf16x8 b0 = *(const bf16x8*)(wb);
            bf16x8 b1 = *(const bf16x8*)(wb + (size_t)64 * 8);
            acc[0] = __builtin_amdgcn_mfma_f32_16x16x32_bf16(a, b0, acc[0], 0, 0, 0);
            acc[1] = __builtin_amdgcn_mfma_f32_16x16x32_bf16(a, b1, acc[1], 0, 0, 0);
        }
#pragma unroll
        for (int nt = 0; nt < 2; nt++) {
            int ch = nt * 16 + n16;
            float bb = bedge[ch];
#pragma unroll
            for (int r = 0; r < 4; r++) {
                int el = w * 16 + quad * 4 + r;      // wave-own row
                size_t ix = (size_t)sek[el] * CED + ch;
                float v = e[ix] + silu_f(acc[nt][r] + bb);
                e[ix] = v;
                short bv = f2bs(v);
                e_bf[ix] = bv;
                feat[el * 296 + 256 + ch] = bv;      // patch LDS tile for msg GEMM (own rows)
            }
        }
    }

    if (DO_MSG) {
        f32x4 acc[8];
#pragma unroll
        for (int t2 = 0; t2 < 8; t2++) acc[t2] = (f32x4){0.f, 0.f, 0.f, 0.f};
#pragma unroll
        for (int kt = 0; kt < 9; kt++) {
            bf16x8 a = *(const bf16x8*)(fbase + kt * 32);
            const short* wb = WpM + ((size_t)(kt * 8) * 64 + lane) * 8;
#pragma unroll
            for (int nt = 0; nt < 8; nt++) {
                bf16x8 b = *(const bf16x8*)(wb + (size_t)nt * 64 * 8);
                acc[nt] = __builtin_amdgcn_mfma_f32_16x16x32_bf16(a, b, acc[nt], 0, 0, 0);
            }
        }
        __syncthreads(); // all feat (bf16) reads done before fp32 alias overwrite
        float* fbuf = (float*)feat; // [64][128] fp32 = 32KB
#pragma unroll
        for (int nt = 0; nt < 8; nt++) {
            int col = nt * 16 + n16;
            float bb = bmsg[col];
#pragma unroll
            for (int r = 0; r < 4; r++) {
                int row = w * 16 + quad * 4 + r;
                fbuf[row * 128 + col] = silu_f(acc[nt][r] + bb);
            }
        }
        __syncthreads();
        // group-reduce by sorted target: one atomic per (distinct target, col)
        if (tid < 128) {
            int c = tid;
            float run = 0.f;
            int cur = sii[0];
            for (int r = 0; r < 64; r++) {
                int tg = sii[r]; // broadcast read
                if (tg != cur) { atomicAdd(&agg[(size_t)cur * CIN + c], run); run = 0.f; cur = tg; }
                run += fbuf[r * 128 + c];
            }
            atomicAdd(&agg[(size_t)cur * CIN + c], run);
        }
    }
}

// ---------------- node update (MFMA): s += silu(cat(s,agg)@Wnode+b); zeroes agg after read -----
__global__ __launch_bounds__(256) void k_node_mfma(
    float* __restrict__ s, short* __restrict__ s_bf, float* __restrict__ agg,
    const short* __restrict__ Wp, const float* __restrict__ bnode)
{
    __shared__ short feat[64 * 264];
    int tid = threadIdx.x;
    int nb0 = blockIdx.x * 64;
    for (int idx = tid; idx < 64 * 16; idx += 256)
        ((uint4*)feat)[(idx >> 4) * 33 + (idx & 15)] = ((const uint4*)s_bf)[(size_t)nb0 * 16 + idx];
    for (int idx = tid; idx < 64 * 32; idx += 256) { // read agg -> bf16, then zero it for next layer
        int kl = idx >> 5, c = idx & 31;
        size_t gix = (size_t)(nb0 + kl) * 32 + c;
        float4 v = ((const float4*)agg)[gix];
        ((float4*)agg)[gix] = (float4){0.f, 0.f, 0.f, 0.f};
        uint2 p; p.x = pack2(v.x, v.y); p.y = pack2(v.z, v.w);
        *(uint2*)&feat[kl * 264 + 128 + 4 * c] = p;
    }
    __syncthreads();
    int lane = tid & 63, w = tid >> 6;
    int quad = lane >> 4, n16 = lane & 15;
    f32x4 acc[8];
#pragma unroll
    for (int t2 = 0; t2 < 8; t2++) acc[t2] = (f32x4){0.f, 0.f, 0.f, 0.f};
    const short* fbase = feat + (w * 16 + n16) * 264 + quad * 8;
#pragma unroll
    for (int kt = 0; kt < 8; kt++) {
        bf16x8 a = *(const bf16x8*)(fbase + kt * 32);
        const short* wb = Wp + ((size_t)(kt * 8) * 64 + lane) * 8;
#pragma unroll
        for (int nt = 0; nt < 8; nt++) {
            bf16x8 b = *(const bf16x8*)(wb + (size_t)nt * 64 * 8);
            acc[nt] = __builtin_amdgcn_mfma_f32_16x16x32_bf16(a, b, acc[nt], 0, 0, 0);
        }
    }
#pragma unroll
    for (int nt = 0; nt < 8; nt++) {
        int col = nt * 16 + n16;
        float bb = bnode[col];
#pragma unroll
        for (int r = 0; r < 4; r++) {
            int node = nb0 + w * 16 + quad * 4 + r;
            size_t ix = (size_t)node * CIN + col;
            float v = s[ix] + silu_f(acc[nt][r] + bb);
            s[ix] = v;
            s_bf[ix] = f2bs(v);
        }
    }
}

// ---------------- post node (MFMA, chained): s2 = silu(s@Wsh+bsh); al = s2@Wal+bal -------------
__global__ __launch_bounds__(256) void k_post_node_mfma(
    const short* __restrict__ s_bf,
    const short* __restrict__ Wpsh, const float* __restrict__ bsh,
    const short* __restrict__ Wpal, const float* __restrict__ bal,
    float* __restrict__ s2, float* __restrict__ out)
{
    __shared__ short feat[64 * 136];
    int tid = threadIdx.x;
    int nb0 = blockIdx.x * 64;
    for (int idx = tid; idx < 64 * 16; idx += 256)
        ((uint4*)feat)[(idx >> 4) * 17 + (idx & 15)] = ((const uint4*)s_bf)[(size_t)nb0 * 16 + idx];
    __syncthreads();
    int lane = tid & 63, w = tid >> 6;
    int quad = lane >> 4, n16 = lane & 15;
    f32x4 acc[8];
#pragma unroll
    for (int t2 = 0; t2 < 8; t2++) acc[t2] = (f32x4){0.f, 0.f, 0.f, 0.f};
    const short* fbase = feat + (w * 16 + n16) * 136 + quad * 8;
#pragma unroll
    for (int kt = 0; kt < 4; kt++) {
        bf16x8 a = *(const bf16x8*)(fbase + kt * 32);
        const short* wb = Wpsh + ((size_t)(kt * 8) * 64 + lane) * 8;
#pragma unroll
        for (int nt = 0; nt < 8; nt++) {
            bf16x8 b = *(const bf16x8*)(wb + (size_t)nt * 64 * 8);
            acc[nt] = __builtin_amdgcn_mfma_f32_16x16x32_bf16(a, b, acc[nt], 0, 0, 0);
        }
    }
#pragma unroll
    for (int nt = 0; nt < 8; nt++) {
        int col = nt * 16 + n16;
        float bb = bsh[col];
#pragma unroll
        for (int r = 0; r < 4; r++) {
            int row = quad * 4 + r;
            float v = silu_f(acc[nt][r] + bb);
            s2[(size_t)(nb0 + w * 16 + row) * CIN + col] = v;
            feat[(w * 16 + row) * 136 + col] = f2bs(v); // own-wave rows only
        }
    }
    f32x4 acc2[5];
#pragma unroll
    for (int t2 = 0; t2 < 5; t2++) acc2[t2] = (f32x4){0.f, 0.f, 0.f, 0.f};
#pragma unroll
    for (int kt = 0; kt < 4; kt++) {
        bf16x8 a = *(const bf16x8*)(fbase + kt * 32);
        const short* wb = Wpal + ((size_t)(kt * 5) * 64 + lane) * 8;
#pragma unroll
        for (int nt = 0; nt < 5; nt++) {
            bf16x8 b = *(const bf16x8*)(wb + (size_t)nt * 64 * 8);
            acc2[nt] = __builtin_amdgcn_mfma_f32_16x16x32_bf16(a, b, acc2[nt], 0, 0, 0);
        }
    }
#pragma unroll
    for (int nt = 0; nt < 5; nt++) {
        int col = nt * 16 + n16;
        float bb = bal[col];
#pragma unroll
        for (int r = 0; r < 4; r++) {
            int node = nb0 + w * 16 + quad * 4 + r;
            float v = acc2[nt][r] + bb;
            if (col < CFA) out[OFF_AT + node * CFA + col] = v;
            else           out[(size_t)node * CLAT + (col - CFA)] = v;
        }
    }
}

// ---------------- post edge (MFMA): esym@Wbm + silu + Wbl tail ---------------------------------
__global__ __launch_bounds__(256) void k_post_edge_mfma(
    const float* __restrict__ s2, const float* __restrict__ e,
    const int* __restrict__ ii, const int* __restrict__ jj, const int* __restrict__ map,
    const short* __restrict__ Wpbm, const float* __restrict__ bbm,
    const float* __restrict__ Wbl, const float* __restrict__ bbl,
    float* __restrict__ out)
{
    __shared__ int sii[64], sjj[64], skf[64], skb[64];
    __shared__ short esym[64 * 40];
    __shared__ float sbias[64 * 132]; // later aliased as fshT[128][66]
    int tid = threadIdx.x;
    int e0 = blockIdx.x * 64;
    if (tid < 64) sii[tid] = ii[e0 + tid];
    else if (tid < 128) sjj[tid - 64] = jj[e0 + tid - 64];
    __syncthreads();
    if (tid < 64) skf[tid] = map[(size_t)sjj[tid] * NN + sii[tid]];
    else if (tid < 128) skb[tid - 64] = map[(size_t)sii[tid - 64] * NN + sjj[tid - 64]];
    __syncthreads();
    for (int idx = tid; idx < 64 * 8; idx += 256) {
        int kl = idx >> 3, c = idx & 7;
        float4 a = ((const float4*)e)[(size_t)skf[kl] * 8 + c];
        int kb = skb[kl];
        float4 b = {0.f, 0.f, 0.f, 0.f};
        if (kb >= 0) b = ((const float4*)e)[(size_t)kb * 8 + c];
        uint2 p; p.x = pack2(0.5f * (a.x + b.x), 0.5f * (a.y + b.y));
        p.y = pack2(0.5f * (a.z + b.z), 0.5f * (a.w + b.w));
        *(uint2*)&esym[kl * 40 + 4 * c] = p;
    }
    for (int idx = tid; idx < 64 * 32; idx += 256) {
        int kl = idx >> 5, c = idx & 31;
        float4 a = ((const float4*)s2)[(size_t)sii[kl] * 32 + c];
        float4 b = ((const float4*)s2)[(size_t)sjj[kl] * 32 + c];
        float4 v = {a.x + b.x, a.y + b.y, a.z + b.z, a.w + b.w};
        *(float4*)&sbias[kl * 132 + 4 * c] = v;
    }
    __syncthreads();
    int lane = tid & 63, w = tid >> 6;
    int quad = lane >> 4, n16 = lane & 15;
    bf16x8 a = *(const bf16x8*)(esym + (w * 16 + n16) * 40 + quad * 8);
    f32x4 acc[8];
#pragma unroll
    for (int nt = 0; nt < 8; nt++) {
        bf16x8 b = *(const bf16x8*)(Wpbm + ((size_t)nt * 64 + lane) * 8);
        f32x4 zero = {0.f, 0.f, 0.f, 0.f};
        acc[nt] = __builtin_amdgcn_mfma_f32_16x16x32_bf16(a, b, zero, 0, 0, 0);
    }
    float f[8][4];
#pragma unroll
    for (int nt = 0; nt < 8; nt++) {
        int col = nt * 16 + n16;
        float bb = bbm[col];
#pragma unroll
        for (int r = 0; r < 4; r++) {
            int row = w * 16 + quad * 4 + r;
            f[nt][r] = silu_f(acc[nt][r] + bb + sbias[row * 132 + col]);
        }
    }
    __syncthreads();
    float* fshT = sbias;
#pragma unroll
    for (int nt = 0; nt < 8; nt++) {
        int col = nt * 16 + n16;
#pragma unroll
        for (int r = 0; r < 4; r++) {
            int row = w * 16 + quad * 4 + r;
            fshT[col * 66 + row] = f[nt][r];
        }
    }
    __syncthreads();
    for (int idx = tid; idx < 64 * CNB; idx += 256) {
        int kl = idx / CNB, b = idx - kl * CNB;
        float acc3 = bbl[b];
        for (int d = 0; d < CIN; d++) acc3 += fshT[d * 66 + kl] * Wbl[d * CNB + b];
        out[OFF_B + (size_t)(e0 + kl) * CNB + b] = acc3;
    }
}

extern "C" void kernel_launch(void* const* d_in, const int* in_sizes, int n_in,
                              void* d_out, int out_size, void* d_ws, size_t ws_size,
                              hipStream_t stream) {
    const float* x      = (const float*)d_in[0];
    const float* t      = (const float*)d_in[1];
    const float* z      = (const float*)d_in[2];
    const int*   eidx   = (const int*)d_in[3];
    const int*   jj     = eidx;        // edge_index[0] = j
    const int*   ii     = eidx + NE;   // edge_index[1] = i
    const float* ea     = (const float*)d_in[4];
    const int*   batch  = (const int*)d_in[5];
    const int*   beg    = (const int*)d_in[6];
    const float* Wt_a   = (const float*)d_in[7];
    const float* bt_a   = (const float*)d_in[8];
    const float* Wt_b   = (const float*)d_in[9];
    const float* bt_b   = (const float*)d_in[10];
    const float* W_atom = (const float*)d_in[11];
    const float* b_atom = (const float*)d_in[12];
    const float* W_bond = (const float*)d_in[13];
    const float* b_bond = (const float*)d_in[14];
    const float* W_lat  = (const float*)d_in[15];
    const float* b_lat  = (const float*)d_in[16];
    const float* W_at   = (const float*)d_in[17];
    const float* b_at   = (const float*)d_in[18];
    const float* W_bt   = (const float*)d_in[19];
    const float* b_bt   = (const float*)d_in[20];
    const float* Wmsg   = (const float*)d_in[21];
    const float* bmsg   = (const float*)d_in[22];
    const float* Wnode  = (const float*)d_in[23];
    const float* bnode  = (const float*)d_in[24];
    const float* Wedge  = (const float*)d_in[25];
    const float* bedge  = (const float*)d_in[26];
    const float* Wsh    = (const float*)d_in[27];
    const float* bsh    = (const float*)d_in[28];
    const float* Wbm    = (const float*)d_in[29];
    const float* bbm    = (const float*)d_in[30];
    const float* Wbl    = (const float*)d_in[31];
    const float* bbl    = (const float*)d_in[32];
    const float* Wal    = (const float*)d_in[33];
    const float* bal    = (const float*)d_in[34];

    float* s      = (float*)d_ws;                       // N*128 f32
    float* e      = s + (size_t)NN * CIN;               // E*32 f32
    float* agg    = e + (size_t)NE * CED;               // N*128 f32
    int*   cnt    = (int*)(agg + (size_t)NN * CIN);     // N   (zeroed together with agg)
    int*   rowpos = cnt + NN;                           // N
    int*   perm   = rowpos + NN;                        // E
    float* s2     = (float*)(perm + NE);                // N*128 f32
    int*   map    = (int*)(s2 + (size_t)NN * CIN);      // N*N i32
    short* s_bf   = (short*)(map + (size_t)NN * NN);    // N*128 bf16
    short* e_bf   = s_bf + (size_t)NN * CIN;            // E*32 bf16
    short* Wpm    = e_bf + (size_t)NE * CED;
    short* Wpe    = Wpm + (size_t)NL * 9 * 8 * 64 * 8;
    short* Wpn    = Wpe + (size_t)NL * 9 * 2 * 64 * 8;
    short* Wpsh   = Wpn + (size_t)NL * 8 * 8 * 64 * 8;
    short* Wpal   = Wpsh + (size_t)4 * 8 * 64 * 8;
    short* Wpbm   = Wpal + (size_t)4 * 5 * 64 * 8;
    float* out    = (float*)d_out;

    hipMemsetAsync(map, 0xFF, (size_t)NN * NN * sizeof(int), stream);            // -1
    hipMemsetAsync(agg, 0, ((size_t)NN * CIN + NN) * sizeof(float), stream);     // agg + cnt
    k_pack_w<<<720, 256, 0, stream>>>(Wmsg, Wedge, Wnode, Wsh, Wal, Wbm,
                                      Wpm, Wpe, Wpn, Wpsh, Wpal, Wpbm);
    k_init_s<<<NN / 16, 128, 0, stream>>>(x, t, z, batch, Wt_a, bt_a, W_atom, b_atom,
                                          W_lat, b_lat, W_at, b_at, s, s_bf);
    k_init_e<<<NE / 8, 256, 0, stream>>>(ea, t, beg, jj, ii, Wt_b, bt_b, W_bond, b_bond,
                                         W_bt, b_bt, e, e_bf, map, cnt);
    k_prefix<<<1, 256, 0, stream>>>(cnt, rowpos);
    k_perm<<<NE / 256, 256, 0, stream>>>(ii, rowpos, perm);

    // msg_0
    k_fused<false, true><<<NE / 64, 256, 0, stream>>>(s_bf, e_bf, ii, jj, perm,
                                                      nullptr, nullptr, e, e_bf,
                                                      Wpm, bmsg, agg);
    for (int l = 0; l < NL; l++) {
        k_node_mfma<<<NN / 64, 256, 0, stream>>>(s, s_bf, agg,
                                                 Wpn + (size_t)l * 8 * 8 * 64 * 8,
                                                 bnode + l * CIN);
        if (l < NL - 1) {
            // fused edge_l + msg_{l+1}
            k_fused<true, true><<<NE / 64, 256, 0, stream>>>(s_bf, e_bf, ii, jj, perm,
                                                             Wpe + (size_t)l * 9 * 2 * 64 * 8,
                                                             bedge + l * CED, e, e_bf,
                                                             Wpm + (size_t)(l + 1) * 9 * 8 * 64 * 8,
                                                             bmsg + (l + 1) * CIN, agg);
        } else {
            // edge_4 only
            k_fused<true, false><<<NE / 64, 256, 0, stream>>>(s_bf, e_bf, ii, jj, perm,
                                                              Wpe + (size_t)l * 9 * 2 * 64 * 8,
                                                              bedge + l * CED, e, e_bf,
                                                              nullptr, nullptr, agg);
        }
    }
    k_post_node_mfma<<<NN / 64, 256, 0, stream>>>(s_bf, Wpsh, bsh, Wpal, bal, s2, out);
    k_post_edge_mfma<<<NE / 64, 256, 0, stream>>>(s2, e, ii, jj, map, Wpbm, bbm, Wbl, bbl, out);
}